// Round 1
// 5468.077 us; speedup vs baseline: 1.6785x; 1.6785x over previous
//
#include <hip/hip_runtime.h>
#include <math.h>

#define BB   128      // batch
#define T    45
#define E    300
#define HH   1024
#define G4   4096
#define HW   196      // 14*14
#define NPX  (BB*HW)  // 25088
#define C0   1026
#define CM   128
#define CR   130

static __device__ __forceinline__ float sigm(float x) { return 1.f / (1.f + __expf(-x)); }

// ---------------- embedding gather: emb[t][b][e] = lookup[que[b][t]][e] ----------------
__global__ void k_embed(const int* __restrict__ que, const float* __restrict__ lookup,
                        float* __restrict__ emb) {
    int idx = blockIdx.x * 256 + threadIdx.x;
    if (idx >= T * BB * E) return;
    int e = idx % E;
    int n = idx / E;
    int b = n % BB;
    int t = n / BB;
    int q = que[b * T + t];
    emb[idx] = lookup[(size_t)q * E + e];
}

// ---------------- generic NT GEMM: C[m][n] = sum_k A[m][k]*Bw[n][k] (+add)(+bias)(relu) ----------------
template <int BM, int BN, int TM, int TN>
__global__ __launch_bounds__(256) void k_gemm_nt(
    const float* __restrict__ A, int lda,
    const float* __restrict__ Bw, int ldb,
    const float* __restrict__ add,           // may be null; ld assumed == ldc
    const float* __restrict__ bias,          // may be null
    float* __restrict__ C, int ldc,
    int M, int N, int K, int relu) {
    constexpr int KT = 16;
    constexpr int TX = BN / TN;   // 16
    constexpr int TY = BM / TM;   // 16
    __shared__ float As[KT][BM + 4];
    __shared__ float Bs[KT][BN + 4];
    const int tid = threadIdx.x;
    const int tx = tid % TX, ty = tid / TX;
    const int r0 = blockIdx.x * BM, c0 = blockIdx.y * BN;
    float acc[TM][TN] = {};
    for (int k0 = 0; k0 < K; k0 += KT) {
#pragma unroll
        for (int l = tid; l < BM * KT; l += 256) {
            int m = l / KT, k = l % KT;
            int gm = r0 + m, gk = k0 + k;
            As[k][m] = (gm < M && gk < K) ? A[(size_t)gm * lda + gk] : 0.f;
        }
#pragma unroll
        for (int l = tid; l < BN * KT; l += 256) {
            int n = l / KT, k = l % KT;
            int gn = c0 + n, gk = k0 + k;
            Bs[k][n] = (gn < N && gk < K) ? Bw[(size_t)gn * ldb + gk] : 0.f;
        }
        __syncthreads();
#pragma unroll
        for (int k = 0; k < KT; ++k) {
            float ar[TM], br[TN];
#pragma unroll
            for (int i = 0; i < TM; ++i) ar[i] = As[k][ty * TM + i];
#pragma unroll
            for (int j = 0; j < TN; ++j) br[j] = Bs[k][tx * TN + j];
#pragma unroll
            for (int i = 0; i < TM; ++i)
#pragma unroll
                for (int j = 0; j < TN; ++j) acc[i][j] += ar[i] * br[j];
        }
        __syncthreads();
    }
#pragma unroll
    for (int i = 0; i < TM; ++i) {
        int gm = r0 + ty * TM + i;
        if (gm >= M) continue;
#pragma unroll
        for (int j = 0; j < TN; ++j) {
            int gn = c0 + tx * TN + j;
            if (gn >= N) continue;
            float v = acc[i][j];
            if (add) v += add[(size_t)gm * ldc + gn];
            if (bias) v += bias[gn];
            if (relu) v = fmaxf(v, 0.f);
            C[(size_t)gm * ldc + gn] = v;
        }
    }
}

// ---------------- LSTM weight packs (gate-interleaved columns: n = j*4+g, g in {i,f,g,o}) ----
// forward: Wpk[n][0..1023] = Whh[g*HH+j][:]; Wpk[n][1024..1323] = Wih[g*HH+j][:]; pad to 1328
__global__ void k_pack_wf(const float* __restrict__ Whh, const float* __restrict__ Wih,
                          float* __restrict__ out) {
    int idx = blockIdx.x * 256 + threadIdx.x;
    if (idx >= G4 * 1328) return;
    int k = idx % 1328;
    int n = idx / 1328;
    int j = n >> 2, g = n & 3;
    int row = g * HH + j;
    float v;
    if (k < HH) v = Whh[(size_t)row * HH + k];
    else {
        int e = k - HH;
        v = (e < E) ? Wih[(size_t)row * E + e] : 0.f;
    }
    out[idx] = v;
}
// backward (only x-part used): Wpk[n][0..299] = Wih[g*HH+j][:]; pad to 304
__global__ void k_pack_wb(const float* __restrict__ Wih, float* __restrict__ out) {
    int idx = blockIdx.x * 256 + threadIdx.x;
    if (idx >= G4 * 304) return;
    int k = idx % 304;
    int n = idx / 304;
    int j = n >> 2, g = n & 3;
    out[idx] = (k < E) ? Wih[(size_t)(g * HH + j) * E + k] : 0.f;
}
__global__ void k_pack_b4(const float* __restrict__ bih, const float* __restrict__ bhh,
                          float* __restrict__ out) {
    int idx = blockIdx.x * 256 + threadIdx.x;
    if (idx >= G4) return;
    int j = idx >> 2, g = idx & 3;
    out[idx] = bih[g * HH + j] + bhh[g * HH + j];
}

// ---------------- fused LSTM step: gates = [h|emb_t] @ Wpk^T (+b4) -> cell -> h_out,c ------
// Wpk rows are gate-interleaved (n = j*4+g). KP=1328 fwd (xoff=1024), 304 bwd (xoff=0).
// first=1 -> skip h-part (k starts at xoff) and treat c as 0.
__global__ __launch_bounds__(256) void k_lstm_fused(
    const float* __restrict__ h_in, float* __restrict__ c_io,
    const float* __restrict__ emb_t,
    const float* __restrict__ Wpk, int KP,
    const float* __restrict__ b4,
    float* __restrict__ h_out, int first) {
    __shared__ float As[16][36];
    __shared__ float Bs[16][68];
    const int tid = threadIdx.x;
    const int tx = tid & 15, ty = tid >> 4;
    const int r0 = blockIdx.x * 32;
    const int c0 = blockIdx.y * 64;
    const int xoff = KP - 304;
    const int k0s = first ? xoff : 0;
    const int ka = tid & 15, ma = tid >> 4;
    float acc[2][4] = {};
    float rA0, rA1, rB0, rB1, rB2, rB3;

#define LSTM_LD(K0)                                                               \
    {                                                                             \
        int gk = (K0) + ka;                                                       \
        if (gk < xoff) {                                                          \
            rA0 = h_in[(size_t)(r0 + ma) * HH + gk];                              \
            rA1 = h_in[(size_t)(r0 + ma + 16) * HH + gk];                         \
        } else {                                                                  \
            int e = gk - xoff;                                                    \
            rA0 = (e < E) ? emb_t[(size_t)(r0 + ma) * E + e] : 0.f;               \
            rA1 = (e < E) ? emb_t[(size_t)(r0 + ma + 16) * E + e] : 0.f;          \
        }                                                                         \
        const float* wp = Wpk + (size_t)(c0 + ma) * KP + gk;                      \
        rB0 = wp[0];                                                              \
        rB1 = wp[(size_t)16 * KP];                                                \
        rB2 = wp[(size_t)32 * KP];                                                \
        rB3 = wp[(size_t)48 * KP];                                                \
    }

    LSTM_LD(k0s);
    for (int k0 = k0s; k0 < KP; k0 += 16) {
        As[ka][ma] = rA0;
        As[ka][ma + 16] = rA1;
        Bs[ka][ma] = rB0;
        Bs[ka][ma + 16] = rB1;
        Bs[ka][ma + 32] = rB2;
        Bs[ka][ma + 48] = rB3;
        __syncthreads();
        if (k0 + 16 < KP) LSTM_LD(k0 + 16);   // prefetch next tile; latency hides under FMAs
#pragma unroll
        for (int k = 0; k < 16; ++k) {
            float a0 = As[k][ty * 2], a1 = As[k][ty * 2 + 1];
            float br[4];
#pragma unroll
            for (int j = 0; j < 4; ++j) br[j] = Bs[k][tx * 4 + j];
#pragma unroll
            for (int j = 0; j < 4; ++j) {
                acc[0][j] += a0 * br[j];
                acc[1][j] += a1 * br[j];
            }
        }
        __syncthreads();
    }
#undef LSTM_LD
    const int jj = blockIdx.y * 16 + tx;   // unit index (TN=4 aligned to one unit's 4 gates)
#pragma unroll
    for (int i = 0; i < 2; ++i) {
        int b = r0 + ty * 2 + i;
        float gi = acc[i][0] + b4[jj * 4 + 0];
        float gf = acc[i][1] + b4[jj * 4 + 1];
        float gg = acc[i][2] + b4[jj * 4 + 2];
        float go = acc[i][3] + b4[jj * 4 + 3];
        float cp = first ? 0.f : c_io[(size_t)b * HH + jj];
        float cn = sigm(gf) * cp + sigm(gi) * tanhf(gg);
        c_io[(size_t)b * HH + jj] = cn;
        h_out[(size_t)b * HH + jj] = sigm(go) * tanhf(cn);
    }
}

// ---------------- enc: l2norm(concat(hf, hb)) per batch row -> out[b][0..2047] ----------------
__global__ void k_enc(const float* __restrict__ hf, const float* __restrict__ hb,
                      float* __restrict__ out) {
    int b = blockIdx.x;
    int tid = threadIdx.x;  // 256
    float vals[8];
    float ss = 0.f;
#pragma unroll
    for (int i = 0; i < 8; ++i) {
        int j = i * 256 + tid;
        float v = (j < HH) ? hf[(size_t)b * HH + j] : hb[(size_t)b * HH + (j - HH)];
        vals[i] = v;
        ss += v * v;
    }
    __shared__ float red[256];
    red[tid] = ss;
    __syncthreads();
    for (int s = 128; s > 0; s >>= 1) {
        if (tid < s) red[tid] += red[tid + s];
        __syncthreads();
    }
    float scale = 1.f / fmaxf(sqrtf(red[0]), 1e-12f);
#pragma unroll
    for (int i = 0; i < 8; ++i) out[(size_t)b * 2048 + i * 256 + tid] = vals[i] * scale;
}

// ---------------- per-pixel sum of squares over 1024 channels (atomic partial) ----------------
__global__ void k_pixssq(const float* __restrict__ img, float* __restrict__ ssq) {
    int b = blockIdx.x >> 4;
    int cc = (blockIdx.x & 15) * 64;
    int p = threadIdx.x;
    if (p >= HW) return;
    const float* base = img + ((size_t)b * 1024 + cc) * HW + p;
    float acc = 0.f;
#pragma unroll 4
    for (int c = 0; c < 64; ++c) {
        float v = base[(size_t)c * HW];
        acc += v * v;
    }
    atomicAdd(&ssq[b * HW + p], acc);
}

__global__ void k_invn(float* __restrict__ ssq) {
    int i = blockIdx.x * 256 + threadIdx.x;
    if (i >= NPX) return;
    ssq[i] = 1.f / fmaxf(sqrtf(ssq[i]), 1e-12f);
}

// ---------------- weight pack: wpk[tap][c][o] = w[o][c][tap] ----------------
__global__ void k_packw(const float* __restrict__ w, float* __restrict__ wpk, int OC, int CIN) {
    int idx = blockIdx.x * 256 + threadIdx.x;
    int total = OC * CIN * 9;
    if (idx >= total) return;
    int o = idx % OC;
    int rest = idx / OC;
    int c = rest % CIN;
    int tap = rest / CIN;
    wpk[idx] = w[((size_t)o * CIN + c) * 9 + tap];
}

// ---------------- conv0: 3x3 pad1, channel-major img, fused l2norm + coord channels ----------
// Halo A-tile staged ONCE per k0 and reused for all 9 taps; Bs holds all 9 taps per k0.
// Thread tile TM=2 (pixels) x TN=8 (ochans): 4 LDS-read instrs per 16 FMAs.
__global__ __launch_bounds__(256) void k_conv0(const float* __restrict__ img,
                                               const float* __restrict__ invn,
                                               const float* __restrict__ wpk,
                                               const float* __restrict__ bias,
                                               float* __restrict__ out) {
    __shared__ float As[16][100];       // [k][halo slot]; slot 96 is the zero slot
    __shared__ float Bs[9][16][68];     // [tap][k][o]
    const int tid = threadIdx.x;
    const int tx = tid & 7, ty = tid >> 3;
    const int bimg = blockIdx.x >> 2, pt = blockIdx.x & 3;
    const int o0 = blockIdx.y * 64;
    const int p0 = pt * 64;
    float acc[2][8] = {};
    const int pv0 = p0 + ty * 2, pv1 = pv0 + 1;
    const int y0 = pv0 / 14, x0p = pv0 % 14;
    const int y1 = pv1 / 14, x1p = pv1 % 14;
    if (tid < 16) As[tid][96] = 0.f;
    for (int k0 = 0; k0 < 1040; k0 += 16) {
        // stage halo A (96 pixel slots x 16 channels), normalized, coords at 1024/1025
        for (int l = tid; l < 1536; l += 256) {
            int s = l % 96, k = l / 96;
            int pn = p0 - 16 + s, gk = k0 + k;
            float v = 0.f;
            if (pn >= 0 && pn < HW && gk < C0) {
                if (gk < 1024) v = img[((size_t)bimg * 1024 + gk) * HW + pn] * invn[bimg * HW + pn];
                else if (gk == 1024) v = (float)(pn / 14 - 7) * (1.f / 7.f);
                else v = (float)(pn % 14 - 7) * (1.f / 7.f);
            }
            As[k][s] = v;
        }
        // stage all 9 taps' weights for this k0
        for (int l = tid; l < 9216; l += 256) {
            int n = l & 63, k = (l >> 6) & 15, tap = l >> 10;
            int gk = k0 + k;
            Bs[tap][k][n] = (gk < C0) ? wpk[((size_t)tap * C0 + gk) * CM + o0 + n] : 0.f;
        }
        __syncthreads();
        for (int tap = 0; tap < 9; ++tap) {
            const int ky = tap / 3 - 1, kx = tap % 3 - 1;
            int of0, of1;
            {
                int ny = y0 + ky, nx = x0p + kx;
                of0 = (pv0 < HW && (unsigned)ny < 14u && (unsigned)nx < 14u)
                          ? (pv0 + ky * 14 + kx) - (p0 - 16) : 96;
            }
            {
                int ny = y1 + ky, nx = x1p + kx;
                of1 = (pv1 < HW && (unsigned)ny < 14u && (unsigned)nx < 14u)
                          ? (pv1 + ky * 14 + kx) - (p0 - 16) : 96;
            }
#pragma unroll
            for (int k = 0; k < 16; ++k) {
                float br[8];
#pragma unroll
                for (int j = 0; j < 8; ++j) br[j] = Bs[tap][k][tx * 8 + j];
                float a0 = As[k][of0], a1 = As[k][of1];
#pragma unroll
                for (int j = 0; j < 8; ++j) {
                    acc[0][j] += a0 * br[j];
                    acc[1][j] += a1 * br[j];
                }
            }
        }
        __syncthreads();
    }
#pragma unroll
    for (int i = 0; i < 2; ++i) {
        int pp = p0 + ty * 2 + i;
        if (pp >= HW) continue;
#pragma unroll
        for (int j = 0; j < 8; ++j) {
            int o = o0 + tx * 8 + j;
            out[((size_t)bimg * HW + pp) * CM + o] = acc[i][j] + bias[o];
        }
    }
}

// ---------------- 3x3 pad1 conv on pixel-major input [NPX][128], halo-staged ----------------
__global__ __launch_bounds__(256) void k_conv_pm(const float* __restrict__ vin,
                                                 const float* __restrict__ wpk,
                                                 const float* __restrict__ bias,
                                                 float* __restrict__ out) {
    __shared__ float As[16][100];
    __shared__ float Bs[9][16][68];
    const int tid = threadIdx.x;
    const int tx = tid & 7, ty = tid >> 3;
    const int bimg = blockIdx.x >> 2, pt = blockIdx.x & 3;
    const int o0 = blockIdx.y * 64;
    const int p0 = pt * 64;
    float acc[2][8] = {};
    const int pv0 = p0 + ty * 2, pv1 = pv0 + 1;
    const int y0 = pv0 / 14, x0p = pv0 % 14;
    const int y1 = pv1 / 14, x1p = pv1 % 14;
    if (tid < 16) As[tid][96] = 0.f;
    for (int k0 = 0; k0 < CM; k0 += 16) {
        for (int l = tid; l < 1536; l += 256) {
            int k = l & 15, s = l >> 4;
            int pn = p0 - 16 + s;
            As[k][s] = (pn >= 0 && pn < HW) ? vin[((size_t)bimg * HW + pn) * CM + k0 + k] : 0.f;
        }
        for (int l = tid; l < 9216; l += 256) {
            int n = l & 63, k = (l >> 6) & 15, tap = l >> 10;
            Bs[tap][k][n] = wpk[((size_t)tap * CM + k0 + k) * CM + o0 + n];
        }
        __syncthreads();
        for (int tap = 0; tap < 9; ++tap) {
            const int ky = tap / 3 - 1, kx = tap % 3 - 1;
            int of0, of1;
            {
                int ny = y0 + ky, nx = x0p + kx;
                of0 = (pv0 < HW && (unsigned)ny < 14u && (unsigned)nx < 14u)
                          ? (pv0 + ky * 14 + kx) - (p0 - 16) : 96;
            }
            {
                int ny = y1 + ky, nx = x1p + kx;
                of1 = (pv1 < HW && (unsigned)ny < 14u && (unsigned)nx < 14u)
                          ? (pv1 + ky * 14 + kx) - (p0 - 16) : 96;
            }
#pragma unroll
            for (int k = 0; k < 16; ++k) {
                float br[8];
#pragma unroll
                for (int j = 0; j < 8; ++j) br[j] = Bs[tap][k][tx * 8 + j];
                float a0 = As[k][of0], a1 = As[k][of1];
#pragma unroll
                for (int j = 0; j < 8; ++j) {
                    acc[0][j] += a0 * br[j];
                    acc[1][j] += a1 * br[j];
                }
            }
        }
        __syncthreads();
    }
#pragma unroll
    for (int i = 0; i < 2; ++i) {
        int pp = p0 + ty * 2 + i;
        if (pp >= HW) continue;
#pragma unroll
        for (int j = 0; j < 8; ++j) {
            int o = o0 + tx * 8 + j;
            out[((size_t)bimg * HW + pp) * CM + o] = acc[i][j] + bias[o];
        }
    }
}

// ---------------- BN train stats: sum & sumsq per channel ----------------
__global__ void k_bnstats(const float* __restrict__ x, float* __restrict__ stats) {
    int r0 = blockIdx.x * 224;  // 112 blocks * 224 rows = 25088
    int c = threadIdx.x & 127, rh = threadIdx.x >> 7;
    float s = 0.f, ss = 0.f;
    for (int r = r0 + rh; r < r0 + 224; r += 2) {
        float v = x[(size_t)r * CM + c];
        s += v;
        ss += v * v;
    }
    __shared__ float rs[256], rss[256];
    rs[threadIdx.x] = s;
    rss[threadIdx.x] = ss;
    __syncthreads();
    if (threadIdx.x < 128) {
        s = rs[threadIdx.x] + rs[threadIdx.x + 128];
        ss = rss[threadIdx.x] + rss[threadIdx.x + 128];
        atomicAdd(&stats[c], s);
        atomicAdd(&stats[128 + c], ss);
    }
}

__global__ void k_bnfinal(const float* __restrict__ stats, const float* __restrict__ g,
                          const float* __restrict__ b, float* __restrict__ scsh) {
    int c = threadIdx.x;
    if (c >= 128) return;
    float mean = stats[c] / (float)NPX;
    float var = stats[128 + c] / (float)NPX - mean * mean;
    float sc = g[c] * rsqrtf(var + 1e-5f);
    scsh[c] = sc;
    scsh[128 + c] = b[c] - mean * sc;
}

// ---------------- relu(bn(x)) (+addv) -> vinr[p][c] (stride 130) ----------------
__global__ void k_apply_cat(const float* __restrict__ x, const float* __restrict__ scsh,
                            const float* __restrict__ addv, float* __restrict__ vinr) {
    int idx = blockIdx.x * 256 + threadIdx.x;
    if (idx >= NPX * CM) return;
    int c = idx & 127;
    int p = idx >> 7;
    float v = fmaxf(x[idx] * scsh[c] + scsh[128 + c], 0.f);
    if (addv) v += addv[idx];
    vinr[(size_t)p * CR + c] = v;
}

__global__ void k_coords_r(float* __restrict__ vinr) {
    int p = blockIdx.x * 256 + threadIdx.x;
    if (p >= NPX) return;
    int pp = p % HW;
    int y = pp / 14, x = pp % 14;
    vinr[(size_t)p * CR + 128] = (float)(y - 7) * (1.f / 7.f);
    vinr[(size_t)p * CR + 129] = (float)(x - 7) * (1.f / 7.f);
}

// ---------------- final: relu(bn(x)) + v1, transpose to NCHW output ----------------
__global__ void k_final(const float* __restrict__ x, const float* __restrict__ scsh,
                        const float* __restrict__ addv, float* __restrict__ outv) {
    int idx = blockIdx.x * 256 + threadIdx.x;
    if (idx >= NPX * CM) return;
    int p = idx % HW;
    int o = (idx / HW) & 127;
    int b = idx / (HW * CM);
    size_t pm = ((size_t)b * HW + p) * CM + o;
    outv[idx] = fmaxf(x[pm] * scsh[o] + scsh[128 + o], 0.f) + addv[pm];
}

extern "C" void kernel_launch(void* const* d_in, const int* in_sizes, int n_in,
                              void* d_out, int out_size, void* d_ws, size_t ws_size,
                              hipStream_t stream) {
    const int* que = (const int*)d_in[0];
    const float* img = (const float*)d_in[1];
    const float* lookup = (const float*)d_in[2];
    const float* Wih_f = (const float*)d_in[3];
    const float* Whh_f = (const float*)d_in[4];
    const float* bih_f = (const float*)d_in[5];
    const float* bhh_f = (const float*)d_in[6];
    const float* Wih_b = (const float*)d_in[7];
    const float* Whh_b = (const float*)d_in[8];
    const float* bih_b = (const float*)d_in[9];
    const float* bhh_b = (const float*)d_in[10];
    const float* conv0_w = (const float*)d_in[11];
    const float* conv0_b = (const float*)d_in[12];
    const float* bn0_g = (const float*)d_in[13];
    const float* bn0_b = (const float*)d_in[14];
    const float* r1c1_w = (const float*)d_in[15];
    const float* r1c1_b = (const float*)d_in[16];
    const float* r1c2_w = (const float*)d_in[17];
    const float* r1c2_b = (const float*)d_in[18];
    const float* r1bn_g = (const float*)d_in[19];
    const float* r1bn_b = (const float*)d_in[20];
    const float* r2c1_w = (const float*)d_in[21];
    const float* r2c1_b = (const float*)d_in[22];
    const float* r2c2_w = (const float*)d_in[23];
    const float* r2c2_b = (const float*)d_in[24];
    const float* r2bn_g = (const float*)d_in[25];
    const float* r2bn_b = (const float*)d_in[26];
    float* out = (float*)d_out;

    float* ws = (float*)d_ws;
    // ---- LSTM region (dead once k_enc has run; image region overlays it) ----
    float* emb = ws;                         // 1,728,000
    float* WfPk = emb + 1728000;             // 5,439,488  (4096 x 1328)
    float* WbPk = WfPk + 5439488;            // 1,245,184  (4096 x 304)
    float* b4f = WbPk + 1245184;             // 4,096
    float* b4b = b4f + 4096;                 // 4,096
    float* hA = b4b + 4096;                  // 131,072
    float* hB = hA + 131072;                 // 131,072
    float* cbuf = hB + 131072;               // 131,072
    float* hbb = cbuf + 131072;              // 131,072
    size_t lstm_end = (size_t)(hbb + 131072 - ws);
    // ---- image region (overlays LSTM region; stream order serializes) ----
    float* invn = ws;                        // 25,088
    float* wpk0 = invn + 25088;              // 1,181,952
    float* wpk1 = wpk0 + 1181952;            // 147,456
    float* wpk2 = wpk1 + 147456;             // 147,456
    float* x0 = wpk2 + 147456;               // 3,211,264
    float* vinr = x0 + 3211264;              // 3,261,440
    float* v1 = vinr + 3261440;              // 3,211,264
    float* v2pre = v1 + 3211264;             // 3,211,264
    float* stats = v2pre + 3211264;          // 256
    float* scsh = stats + 256;               // 256
    size_t img_end = (size_t)(scsh + 256 - ws);
    size_t need = (lstm_end > img_end ? lstm_end : img_end) * 4;
    if (ws_size < need) return;  // insufficient workspace; fail loudly via validation

    auto cdiv = [](int a, int b) { return (a + b - 1) / b; };

    // ================= LSTM branch =================
    k_embed<<<cdiv(T * BB * E, 256), 256, 0, stream>>>(que, lookup, emb);
    k_pack_wf<<<cdiv(G4 * 1328, 256), 256, 0, stream>>>(Whh_f, Wih_f, WfPk);
    k_pack_wb<<<cdiv(G4 * 304, 256), 256, 0, stream>>>(Wih_b, WbPk);
    k_pack_b4<<<cdiv(G4, 256), 256, 0, stream>>>(bih_f, bhh_f, b4f);
    k_pack_b4<<<cdiv(G4, 256), 256, 0, stream>>>(bih_b, bhh_b, b4b);
    // backward LSTM: only step 0 (position T-1) is ever used; cbuf is scratch here
    k_lstm_fused<<<dim3(4, 64), 256, 0, stream>>>(hA, cbuf, emb + (size_t)(T - 1) * BB * E,
                                                  WbPk, 304, b4b, hbb, 1);
    // forward LSTM: 45 sequential fused steps (gemm + cell in one kernel)
    float* hp = hA;
    float* hq = hB;
    float* hlast = hA;
    for (int t = 0; t < T; ++t) {
        k_lstm_fused<<<dim3(4, 64), 256, 0, stream>>>(hq, cbuf, emb + (size_t)t * BB * E,
                                                      WfPk, 1328, b4f, hp, t == 0);
        hlast = hp;
        float* tmp = hp; hp = hq; hq = tmp;
    }
    k_enc<<<128, 256, 0, stream>>>(hlast, hbb, out);

    // ================= image branch (reuses LSTM workspace) =================
    hipMemsetAsync(invn, 0, NPX * 4, stream);
    k_pixssq<<<BB * 16, 256, 0, stream>>>(img, invn);
    k_invn<<<cdiv(NPX, 256), 256, 0, stream>>>(invn);
    k_packw<<<cdiv(128 * C0 * 9, 256), 256, 0, stream>>>(conv0_w, wpk0, 128, C0);
    k_packw<<<cdiv(128 * 128 * 9, 256), 256, 0, stream>>>(r1c2_w, wpk1, 128, 128);
    k_packw<<<cdiv(128 * 128 * 9, 256), 256, 0, stream>>>(r2c2_w, wpk2, 128, 128);

    k_conv0<<<dim3(512, 2), 256, 0, stream>>>(img, invn, wpk0, conv0_b, x0);
    hipMemsetAsync(stats, 0, 256 * 4, stream);
    k_bnstats<<<112, 256, 0, stream>>>(x0, stats);
    k_bnfinal<<<1, 128, 0, stream>>>(stats, bn0_g, bn0_b, scsh);
    k_apply_cat<<<cdiv(NPX * CM, 256), 256, 0, stream>>>(x0, scsh, nullptr, vinr);
    k_coords_r<<<cdiv(NPX, 256), 256, 0, stream>>>(vinr);

    // resblock 1
    k_gemm_nt<64, 64, 4, 4><<<dim3(392, 2), 256, 0, stream>>>(
        vinr, CR, r1c1_w, CR, nullptr, r1c1_b, v1, CM, NPX, CM, CR, 1);
    k_conv_pm<<<dim3(512, 2), 256, 0, stream>>>(v1, wpk1, r1c2_b, v2pre);
    hipMemsetAsync(stats, 0, 256 * 4, stream);
    k_bnstats<<<112, 256, 0, stream>>>(v2pre, stats);
    k_bnfinal<<<1, 128, 0, stream>>>(stats, r1bn_g, r1bn_b, scsh);
    k_apply_cat<<<cdiv(NPX * CM, 256), 256, 0, stream>>>(v2pre, scsh, v1, vinr);

    // resblock 2
    k_gemm_nt<64, 64, 4, 4><<<dim3(392, 2), 256, 0, stream>>>(
        vinr, CR, r2c1_w, CR, nullptr, r2c1_b, v1, CM, NPX, CM, CR, 1);
    k_conv_pm<<<dim3(512, 2), 256, 0, stream>>>(v1, wpk2, r2c2_b, v2pre);
    hipMemsetAsync(stats, 0, 256 * 4, stream);
    k_bnstats<<<112, 256, 0, stream>>>(v2pre, stats);
    k_bnfinal<<<1, 128, 0, stream>>>(stats, r2bn_g, r2bn_b, scsh);
    k_final<<<cdiv(NPX * CM, 256), 256, 0, stream>>>(v2pre, scsh, v1, out + (size_t)BB * 2048);
}

// Round 2
// 4040.888 us; speedup vs baseline: 2.2713x; 1.3532x over previous
//
#include <hip/hip_runtime.h>
#include <math.h>

#define BB   128      // batch
#define T    45
#define E    300
#define HH   1024
#define G4   4096
#define HW   196      // 14*14
#define NPX  (BB*HW)  // 25088
#define C0   1026
#define CM   128
#define CR   130

static __device__ __forceinline__ float sigm(float x) { return 1.f / (1.f + __expf(-x)); }

// ---------------- embedding gather: emb[t][b][e] = lookup[que[b][t]][e] ----------------
__global__ void k_embed(const int* __restrict__ que, const float* __restrict__ lookup,
                        float* __restrict__ emb) {
    int idx = blockIdx.x * 256 + threadIdx.x;
    if (idx >= T * BB * E) return;
    int e = idx % E;
    int n = idx / E;
    int b = n % BB;
    int t = n / BB;
    int q = que[b * T + t];
    emb[idx] = lookup[(size_t)q * E + e];
}

// ---------------- generic NT GEMM: C[m][n] = sum_k A[m][k]*Bw[n][k] (+add)(+bias)(relu) ----------------
template <int BM, int BN, int TM, int TN>
__global__ __launch_bounds__(256) void k_gemm_nt(
    const float* __restrict__ A, int lda,
    const float* __restrict__ Bw, int ldb,
    const float* __restrict__ add,           // may be null; ld assumed == ldc
    const float* __restrict__ bias,          // may be null
    float* __restrict__ C, int ldc,
    int M, int N, int K, int relu) {
    constexpr int KT = 16;
    constexpr int TX = BN / TN;   // 16
    constexpr int TY = BM / TM;   // 16
    __shared__ float As[KT][BM + 4];
    __shared__ float Bs[KT][BN + 4];
    const int tid = threadIdx.x;
    const int tx = tid % TX, ty = tid / TX;
    const int r0 = blockIdx.x * BM, c0 = blockIdx.y * BN;
    float acc[TM][TN] = {};
    for (int k0 = 0; k0 < K; k0 += KT) {
#pragma unroll
        for (int l = tid; l < BM * KT; l += 256) {
            int m = l / KT, k = l % KT;
            int gm = r0 + m, gk = k0 + k;
            As[k][m] = (gm < M && gk < K) ? A[(size_t)gm * lda + gk] : 0.f;
        }
#pragma unroll
        for (int l = tid; l < BN * KT; l += 256) {
            int n = l / KT, k = l % KT;
            int gn = c0 + n, gk = k0 + k;
            Bs[k][n] = (gn < N && gk < K) ? Bw[(size_t)gn * ldb + gk] : 0.f;
        }
        __syncthreads();
#pragma unroll
        for (int k = 0; k < KT; ++k) {
            float ar[TM], br[TN];
#pragma unroll
            for (int i = 0; i < TM; ++i) ar[i] = As[k][ty * TM + i];
#pragma unroll
            for (int j = 0; j < TN; ++j) br[j] = Bs[k][tx * TN + j];
#pragma unroll
            for (int i = 0; i < TM; ++i)
#pragma unroll
                for (int j = 0; j < TN; ++j) acc[i][j] += ar[i] * br[j];
        }
        __syncthreads();
    }
#pragma unroll
    for (int i = 0; i < TM; ++i) {
        int gm = r0 + ty * TM + i;
        if (gm >= M) continue;
#pragma unroll
        for (int j = 0; j < TN; ++j) {
            int gn = c0 + tx * TN + j;
            if (gn >= N) continue;
            float v = acc[i][j];
            if (add) v += add[(size_t)gm * ldc + gn];
            if (bias) v += bias[gn];
            if (relu) v = fmaxf(v, 0.f);
            C[(size_t)gm * ldc + gn] = v;
        }
    }
}

// ---------------- LSTM weight packs (gate-interleaved columns: n = j*4+g, g in {i,f,g,o}) ----
__global__ void k_pack_wf(const float* __restrict__ Whh, const float* __restrict__ Wih,
                          float* __restrict__ out) {
    int idx = blockIdx.x * 256 + threadIdx.x;
    if (idx >= G4 * 1328) return;
    int k = idx % 1328;
    int n = idx / 1328;
    int j = n >> 2, g = n & 3;
    int row = g * HH + j;
    float v;
    if (k < HH) v = Whh[(size_t)row * HH + k];
    else {
        int e = k - HH;
        v = (e < E) ? Wih[(size_t)row * E + e] : 0.f;
    }
    out[idx] = v;
}
__global__ void k_pack_wb(const float* __restrict__ Wih, float* __restrict__ out) {
    int idx = blockIdx.x * 256 + threadIdx.x;
    if (idx >= G4 * 304) return;
    int k = idx % 304;
    int n = idx / 304;
    int j = n >> 2, g = n & 3;
    out[idx] = (k < E) ? Wih[(size_t)(g * HH + j) * E + k] : 0.f;
}
__global__ void k_pack_b4(const float* __restrict__ bih, const float* __restrict__ bhh,
                          float* __restrict__ out) {
    int idx = blockIdx.x * 256 + threadIdx.x;
    if (idx >= G4) return;
    int j = idx >> 2, g = idx & 3;
    out[idx] = bih[g * HH + j] + bhh[g * HH + j];
}

// ---------------- fused LSTM step ----------------
__global__ __launch_bounds__(256) void k_lstm_fused(
    const float* __restrict__ h_in, float* __restrict__ c_io,
    const float* __restrict__ emb_t,
    const float* __restrict__ Wpk, int KP,
    const float* __restrict__ b4,
    float* __restrict__ h_out, int first) {
    __shared__ float As[16][36];
    __shared__ float Bs[16][68];
    const int tid = threadIdx.x;
    const int tx = tid & 15, ty = tid >> 4;
    const int r0 = blockIdx.x * 32;
    const int c0 = blockIdx.y * 64;
    const int xoff = KP - 304;
    const int k0s = first ? xoff : 0;
    const int ka = tid & 15, ma = tid >> 4;
    float acc[2][4] = {};
    float rA0, rA1, rB0, rB1, rB2, rB3;

#define LSTM_LD(K0)                                                               \
    {                                                                             \
        int gk = (K0) + ka;                                                       \
        if (gk < xoff) {                                                          \
            rA0 = h_in[(size_t)(r0 + ma) * HH + gk];                              \
            rA1 = h_in[(size_t)(r0 + ma + 16) * HH + gk];                         \
        } else {                                                                  \
            int e = gk - xoff;                                                    \
            rA0 = (e < E) ? emb_t[(size_t)(r0 + ma) * E + e] : 0.f;               \
            rA1 = (e < E) ? emb_t[(size_t)(r0 + ma + 16) * E + e] : 0.f;          \
        }                                                                         \
        const float* wp = Wpk + (size_t)(c0 + ma) * KP + gk;                      \
        rB0 = wp[0];                                                              \
        rB1 = wp[(size_t)16 * KP];                                                \
        rB2 = wp[(size_t)32 * KP];                                                \
        rB3 = wp[(size_t)48 * KP];                                                \
    }

    LSTM_LD(k0s);
    for (int k0 = k0s; k0 < KP; k0 += 16) {
        As[ka][ma] = rA0;
        As[ka][ma + 16] = rA1;
        Bs[ka][ma] = rB0;
        Bs[ka][ma + 16] = rB1;
        Bs[ka][ma + 32] = rB2;
        Bs[ka][ma + 48] = rB3;
        __syncthreads();
        if (k0 + 16 < KP) LSTM_LD(k0 + 16);
#pragma unroll
        for (int k = 0; k < 16; ++k) {
            float a0 = As[k][ty * 2], a1 = As[k][ty * 2 + 1];
            float br[4];
#pragma unroll
            for (int j = 0; j < 4; ++j) br[j] = Bs[k][tx * 4 + j];
#pragma unroll
            for (int j = 0; j < 4; ++j) {
                acc[0][j] += a0 * br[j];
                acc[1][j] += a1 * br[j];
            }
        }
        __syncthreads();
    }
#undef LSTM_LD
    const int jj = blockIdx.y * 16 + tx;
#pragma unroll
    for (int i = 0; i < 2; ++i) {
        int b = r0 + ty * 2 + i;
        float gi = acc[i][0] + b4[jj * 4 + 0];
        float gf = acc[i][1] + b4[jj * 4 + 1];
        float gg = acc[i][2] + b4[jj * 4 + 2];
        float go = acc[i][3] + b4[jj * 4 + 3];
        float cp = first ? 0.f : c_io[(size_t)b * HH + jj];
        float cn = sigm(gf) * cp + sigm(gi) * tanhf(gg);
        c_io[(size_t)b * HH + jj] = cn;
        h_out[(size_t)b * HH + jj] = sigm(go) * tanhf(cn);
    }
}

// ---------------- enc: l2norm(concat(hf, hb)) per batch row -> out[b][0..2047] ----------------
__global__ void k_enc(const float* __restrict__ hf, const float* __restrict__ hb,
                      float* __restrict__ out) {
    int b = blockIdx.x;
    int tid = threadIdx.x;  // 256
    float vals[8];
    float ss = 0.f;
#pragma unroll
    for (int i = 0; i < 8; ++i) {
        int j = i * 256 + tid;
        float v = (j < HH) ? hf[(size_t)b * HH + j] : hb[(size_t)b * HH + (j - HH)];
        vals[i] = v;
        ss += v * v;
    }
    __shared__ float red[256];
    red[tid] = ss;
    __syncthreads();
    for (int s = 128; s > 0; s >>= 1) {
        if (tid < s) red[tid] += red[tid + s];
        __syncthreads();
    }
    float scale = 1.f / fmaxf(sqrtf(red[0]), 1e-12f);
#pragma unroll
    for (int i = 0; i < 8; ++i) out[(size_t)b * 2048 + i * 256 + tid] = vals[i] * scale;
}

// ---------------- per-pixel sum of squares over 1024 channels (atomic partial) ----------------
__global__ void k_pixssq(const float* __restrict__ img, float* __restrict__ ssq) {
    int b = blockIdx.x >> 4;
    int cc = (blockIdx.x & 15) * 64;
    int p = threadIdx.x;
    if (p >= HW) return;
    const float* base = img + ((size_t)b * 1024 + cc) * HW + p;
    float acc = 0.f;
#pragma unroll 4
    for (int c = 0; c < 64; ++c) {
        float v = base[(size_t)c * HW];
        acc += v * v;
    }
    atomicAdd(&ssq[b * HW + p], acc);
}

__global__ void k_invn(float* __restrict__ ssq) {
    int i = blockIdx.x * 256 + threadIdx.x;
    if (i >= NPX) return;
    ssq[i] = 1.f / fmaxf(sqrtf(ssq[i]), 1e-12f);
}

// ---------------- weight packs for REG-B convs: Bpk[ocg][tap][k][16 oc] ----------------
__global__ void k_packB0(const float* __restrict__ w, float* __restrict__ o) {
    int idx = blockIdx.x * 256 + threadIdx.x;
    if (idx >= 8 * 9 * 1040 * 16) return;
    int oi = idx & 15;
    int r = idx >> 4;        // (ocg*9+tap)*1040 + c
    int c = r % 1040;
    int gt = r / 1040;       // ocg*9+tap
    int tap = gt % 9, ocg = gt / 9;
    o[idx] = (c < C0) ? w[((size_t)(ocg * 16 + oi) * C0 + c) * 9 + tap] : 0.f;
}
__global__ void k_packBpm(const float* __restrict__ w, float* __restrict__ o) {
    int idx = blockIdx.x * 256 + threadIdx.x;
    if (idx >= 8 * 9 * 128 * 16) return;
    int oi = idx & 15;
    int r = idx >> 4;
    int c = r % 128;
    int gt = r / 128;
    int tap = gt % 9, ocg = gt / 9;
    o[idx] = w[((size_t)(ocg * 16 + oi) * 128 + c) * 9 + tap];
}

// ---------------- conv0: lane = global pixel, B streamed via uniform (scalar) loads --------
// Block: 256 global pixels x 16 ochans. A halo tile in LDS [289][20] (row stride 80B:
// 16B-aligned for b128, bank-uniform). Per (tap,4k): 1 ds_read_b128 + 16 uniform b128 + 64 FMA.
__global__ __launch_bounds__(256) void k_conv0(const float* __restrict__ img,
                                               const float* __restrict__ invn,
                                               const float* __restrict__ wpk,
                                               const float* __restrict__ bias,
                                               float* __restrict__ out) {
    __shared__ float As[289][20];   // slot 288 = zero row
    const int tid = threadIdx.x;
    const int P0 = blockIdx.x * 256;
    const int g = P0 + tid;          // global pixel, always < NPX (98*256 = 25088)
    const int ocg = blockIdx.y;      // 0..7
    const int p = g % HW;
    const int y = p / 14, x = p % 14;
    float acc[16] = {};
    if (tid < 16) As[288][tid] = 0.f;
    for (int k0 = 0; k0 < 1040; k0 += 16) {
        __syncthreads();
        for (int l = tid; l < 288 * 16; l += 256) {
            int s = l % 288, k = l / 288;
            int gp = P0 - 16 + s;
            float v = 0.f;
            if (gp >= 0 && gp < NPX) {
                int gk = k0 + k;
                int pp = gp % HW;
                if (gk < 1024) v = img[((size_t)(gp / HW) * 1024 + gk) * HW + pp] * invn[gp];
                else if (gk == 1024) v = (float)(pp / 14 - 7) * (1.f / 7.f);
                else if (gk == 1025) v = (float)(pp % 14 - 7) * (1.f / 7.f);
            }
            As[s][k] = v;
        }
        __syncthreads();
        for (int tap = 0; tap < 9; ++tap) {
            const int ky = tap / 3 - 1, kx = tap % 3 - 1;
            const int yy = y + ky, xx = x + kx;
            const int of = ((unsigned)yy < 14u && (unsigned)xx < 14u)
                               ? (tid + 16 + ky * 14 + kx) : 288;
            const float4* __restrict__ wq =
                (const float4*)wpk + ((size_t)(ocg * 9 + tap) * 1040 + k0) * 4;
            for (int kq = 0; kq < 4; ++kq) {
                float4 a4 = *(const float4*)&As[of][kq * 4];
                float av[4] = {a4.x, a4.y, a4.z, a4.w};
#pragma unroll
                for (int kk = 0; kk < 4; ++kk) {
                    float a = av[kk];
                    float4 w0 = wq[0], w1 = wq[1], w2 = wq[2], w3 = wq[3];
                    wq += 4;
                    acc[0]  += a * w0.x;  acc[1]  += a * w0.y;
                    acc[2]  += a * w0.z;  acc[3]  += a * w0.w;
                    acc[4]  += a * w1.x;  acc[5]  += a * w1.y;
                    acc[6]  += a * w1.z;  acc[7]  += a * w1.w;
                    acc[8]  += a * w2.x;  acc[9]  += a * w2.y;
                    acc[10] += a * w2.z;  acc[11] += a * w2.w;
                    acc[12] += a * w3.x;  acc[13] += a * w3.y;
                    acc[14] += a * w3.z;  acc[15] += a * w3.w;
                }
            }
        }
    }
    float* op = out + (size_t)g * CM + ocg * 16;
    const float* bp = bias + ocg * 16;
#pragma unroll
    for (int q = 0; q < 4; ++q) {
        float4 r;
        r.x = acc[q * 4 + 0] + bp[q * 4 + 0];
        r.y = acc[q * 4 + 1] + bp[q * 4 + 1];
        r.z = acc[q * 4 + 2] + bp[q * 4 + 2];
        r.w = acc[q * 4 + 3] + bp[q * 4 + 3];
        *(float4*)&op[q * 4] = r;
    }
}

// ---------------- 3x3 pad1 conv on pixel-major input [NPX][128], REG-B structure ----------
__global__ __launch_bounds__(256) void k_conv_pm(const float* __restrict__ vin,
                                                 const float* __restrict__ wpk,
                                                 const float* __restrict__ bias,
                                                 float* __restrict__ out) {
    __shared__ float As[289][20];
    const int tid = threadIdx.x;
    const int P0 = blockIdx.x * 256;
    const int g = P0 + tid;
    const int ocg = blockIdx.y;
    const int p = g % HW;
    const int y = p / 14, x = p % 14;
    float acc[16] = {};
    if (tid < 16) As[288][tid] = 0.f;
    for (int k0 = 0; k0 < CM; k0 += 16) {
        __syncthreads();
        for (int l = tid; l < 288 * 4; l += 256) {
            int s = l >> 2, kq = l & 3;
            int gp = P0 - 16 + s;
            float4 v;
            v.x = v.y = v.z = v.w = 0.f;
            if (gp >= 0 && gp < NPX) v = *(const float4*)&vin[(size_t)gp * CM + k0 + kq * 4];
            *(float4*)&As[s][kq * 4] = v;
        }
        __syncthreads();
        for (int tap = 0; tap < 9; ++tap) {
            const int ky = tap / 3 - 1, kx = tap % 3 - 1;
            const int yy = y + ky, xx = x + kx;
            const int of = ((unsigned)yy < 14u && (unsigned)xx < 14u)
                               ? (tid + 16 + ky * 14 + kx) : 288;
            const float4* __restrict__ wq =
                (const float4*)wpk + ((size_t)(ocg * 9 + tap) * 128 + k0) * 4;
            for (int kq = 0; kq < 4; ++kq) {
                float4 a4 = *(const float4*)&As[of][kq * 4];
                float av[4] = {a4.x, a4.y, a4.z, a4.w};
#pragma unroll
                for (int kk = 0; kk < 4; ++kk) {
                    float a = av[kk];
                    float4 w0 = wq[0], w1 = wq[1], w2 = wq[2], w3 = wq[3];
                    wq += 4;
                    acc[0]  += a * w0.x;  acc[1]  += a * w0.y;
                    acc[2]  += a * w0.z;  acc[3]  += a * w0.w;
                    acc[4]  += a * w1.x;  acc[5]  += a * w1.y;
                    acc[6]  += a * w1.z;  acc[7]  += a * w1.w;
                    acc[8]  += a * w2.x;  acc[9]  += a * w2.y;
                    acc[10] += a * w2.z;  acc[11] += a * w2.w;
                    acc[12] += a * w3.x;  acc[13] += a * w3.y;
                    acc[14] += a * w3.z;  acc[15] += a * w3.w;
                }
            }
        }
    }
    float* op = out + (size_t)g * CM + ocg * 16;
    const float* bp = bias + ocg * 16;
#pragma unroll
    for (int q = 0; q < 4; ++q) {
        float4 r;
        r.x = acc[q * 4 + 0] + bp[q * 4 + 0];
        r.y = acc[q * 4 + 1] + bp[q * 4 + 1];
        r.z = acc[q * 4 + 2] + bp[q * 4 + 2];
        r.w = acc[q * 4 + 3] + bp[q * 4 + 3];
        *(float4*)&op[q * 4] = r;
    }
}

// ---------------- BN train stats: sum & sumsq per channel ----------------
__global__ void k_bnstats(const float* __restrict__ x, float* __restrict__ stats) {
    int r0 = blockIdx.x * 224;  // 112 blocks * 224 rows = 25088
    int c = threadIdx.x & 127, rh = threadIdx.x >> 7;
    float s = 0.f, ss = 0.f;
    for (int r = r0 + rh; r < r0 + 224; r += 2) {
        float v = x[(size_t)r * CM + c];
        s += v;
        ss += v * v;
    }
    __shared__ float rs[256], rss[256];
    rs[threadIdx.x] = s;
    rss[threadIdx.x] = ss;
    __syncthreads();
    if (threadIdx.x < 128) {
        s = rs[threadIdx.x] + rs[threadIdx.x + 128];
        ss = rss[threadIdx.x] + rss[threadIdx.x + 128];
        atomicAdd(&stats[c], s);
        atomicAdd(&stats[128 + c], ss);
    }
}

__global__ void k_bnfinal(const float* __restrict__ stats, const float* __restrict__ g,
                          const float* __restrict__ b, float* __restrict__ scsh) {
    int c = threadIdx.x;
    if (c >= 128) return;
    float mean = stats[c] / (float)NPX;
    float var = stats[128 + c] / (float)NPX - mean * mean;
    float sc = g[c] * rsqrtf(var + 1e-5f);
    scsh[c] = sc;
    scsh[128 + c] = b[c] - mean * sc;
}

// ---------------- relu(bn(x)) (+addv) -> vinr[p][c] (stride 130) ----------------
__global__ void k_apply_cat(const float* __restrict__ x, const float* __restrict__ scsh,
                            const float* __restrict__ addv, float* __restrict__ vinr) {
    int idx = blockIdx.x * 256 + threadIdx.x;
    if (idx >= NPX * CM) return;
    int c = idx & 127;
    int p = idx >> 7;
    float v = fmaxf(x[idx] * scsh[c] + scsh[128 + c], 0.f);
    if (addv) v += addv[idx];
    vinr[(size_t)p * CR + c] = v;
}

__global__ void k_coords_r(float* __restrict__ vinr) {
    int p = blockIdx.x * 256 + threadIdx.x;
    if (p >= NPX) return;
    int pp = p % HW;
    int y = pp / 14, x = pp % 14;
    vinr[(size_t)p * CR + 128] = (float)(y - 7) * (1.f / 7.f);
    vinr[(size_t)p * CR + 129] = (float)(x - 7) * (1.f / 7.f);
}

// ---------------- final: relu(bn(x)) + v1, transpose to NCHW output ----------------
__global__ void k_final(const float* __restrict__ x, const float* __restrict__ scsh,
                        const float* __restrict__ addv, float* __restrict__ outv) {
    int idx = blockIdx.x * 256 + threadIdx.x;
    if (idx >= NPX * CM) return;
    int p = idx % HW;
    int o = (idx / HW) & 127;
    int b = idx / (HW * CM);
    size_t pm = ((size_t)b * HW + p) * CM + o;
    outv[idx] = fmaxf(x[pm] * scsh[o] + scsh[128 + o], 0.f) + addv[pm];
}

extern "C" void kernel_launch(void* const* d_in, const int* in_sizes, int n_in,
                              void* d_out, int out_size, void* d_ws, size_t ws_size,
                              hipStream_t stream) {
    const int* que = (const int*)d_in[0];
    const float* img = (const float*)d_in[1];
    const float* lookup = (const float*)d_in[2];
    const float* Wih_f = (const float*)d_in[3];
    const float* Whh_f = (const float*)d_in[4];
    const float* bih_f = (const float*)d_in[5];
    const float* bhh_f = (const float*)d_in[6];
    const float* Wih_b = (const float*)d_in[7];
    const float* Whh_b = (const float*)d_in[8];
    const float* bih_b = (const float*)d_in[9];
    const float* bhh_b = (const float*)d_in[10];
    const float* conv0_w = (const float*)d_in[11];
    const float* conv0_b = (const float*)d_in[12];
    const float* bn0_g = (const float*)d_in[13];
    const float* bn0_b = (const float*)d_in[14];
    const float* r1c1_w = (const float*)d_in[15];
    const float* r1c1_b = (const float*)d_in[16];
    const float* r1c2_w = (const float*)d_in[17];
    const float* r1c2_b = (const float*)d_in[18];
    const float* r1bn_g = (const float*)d_in[19];
    const float* r1bn_b = (const float*)d_in[20];
    const float* r2c1_w = (const float*)d_in[21];
    const float* r2c1_b = (const float*)d_in[22];
    const float* r2c2_w = (const float*)d_in[23];
    const float* r2c2_b = (const float*)d_in[24];
    const float* r2bn_g = (const float*)d_in[25];
    const float* r2bn_b = (const float*)d_in[26];
    float* out = (float*)d_out;

    float* ws = (float*)d_ws;
    // ---- LSTM region (dead once k_enc has run; image region overlays it) ----
    float* emb = ws;                         // 1,728,000
    float* WfPk = emb + 1728000;             // 5,439,488  (4096 x 1328)
    float* WbPk = WfPk + 5439488;            // 1,245,184  (4096 x 304)
    float* b4f = WbPk + 1245184;             // 4,096
    float* b4b = b4f + 4096;                 // 4,096
    float* hA = b4b + 4096;                  // 131,072
    float* hB = hA + 131072;                 // 131,072
    float* cbuf = hB + 131072;               // 131,072
    float* hbb = cbuf + 131072;              // 131,072
    size_t lstm_end = (size_t)(hbb + 131072 - ws);
    // ---- image region (overlays LSTM region; stream order serializes) ----
    float* invn = ws;                        // 25,088
    float* wpk0 = invn + 25088;              // 1,198,080  (8 x 9 x 1040 x 16)
    float* wpk1 = wpk0 + 1198080;            // 147,456    (8 x 9 x 128 x 16)
    float* wpk2 = wpk1 + 147456;             // 147,456
    float* x0 = wpk2 + 147456;               // 3,211,264
    float* vinr = x0 + 3211264;              // 3,261,440
    float* v1 = vinr + 3261440;              // 3,211,264
    float* v2pre = v1 + 3211264;             // 3,211,264
    float* stats = v2pre + 3211264;          // 256
    float* scsh = stats + 256;               // 256
    size_t img_end = (size_t)(scsh + 256 - ws);
    size_t need = (lstm_end > img_end ? lstm_end : img_end) * 4;
    if (ws_size < need) return;  // insufficient workspace; fail loudly via validation

    auto cdiv = [](int a, int b) { return (a + b - 1) / b; };

    // ================= LSTM branch =================
    k_embed<<<cdiv(T * BB * E, 256), 256, 0, stream>>>(que, lookup, emb);
    k_pack_wf<<<cdiv(G4 * 1328, 256), 256, 0, stream>>>(Whh_f, Wih_f, WfPk);
    k_pack_wb<<<cdiv(G4 * 304, 256), 256, 0, stream>>>(Wih_b, WbPk);
    k_pack_b4<<<cdiv(G4, 256), 256, 0, stream>>>(bih_f, bhh_f, b4f);
    k_pack_b4<<<cdiv(G4, 256), 256, 0, stream>>>(bih_b, bhh_b, b4b);
    // backward LSTM: only step 0 (position T-1) is ever used; cbuf is scratch here
    k_lstm_fused<<<dim3(4, 64), 256, 0, stream>>>(hA, cbuf, emb + (size_t)(T - 1) * BB * E,
                                                  WbPk, 304, b4b, hbb, 1);
    // forward LSTM: 45 sequential fused steps (gemm + cell in one kernel)
    float* hp = hA;
    float* hq = hB;
    float* hlast = hA;
    for (int t = 0; t < T; ++t) {
        k_lstm_fused<<<dim3(4, 64), 256, 0, stream>>>(hq, cbuf, emb + (size_t)t * BB * E,
                                                      WfPk, 1328, b4f, hp, t == 0);
        hlast = hp;
        float* tmp = hp; hp = hq; hq = tmp;
    }
    k_enc<<<128, 256, 0, stream>>>(hlast, hbb, out);

    // ================= image branch (reuses LSTM workspace) =================
    hipMemsetAsync(invn, 0, NPX * 4, stream);
    k_pixssq<<<BB * 16, 256, 0, stream>>>(img, invn);
    k_invn<<<cdiv(NPX, 256), 256, 0, stream>>>(invn);
    k_packB0<<<cdiv(8 * 9 * 1040 * 16, 256), 256, 0, stream>>>(conv0_w, wpk0);
    k_packBpm<<<cdiv(8 * 9 * 128 * 16, 256), 256, 0, stream>>>(r1c2_w, wpk1);
    k_packBpm<<<cdiv(8 * 9 * 128 * 16, 256), 256, 0, stream>>>(r2c2_w, wpk2);

    k_conv0<<<dim3(98, 8), 256, 0, stream>>>(img, invn, wpk0, conv0_b, x0);
    hipMemsetAsync(stats, 0, 256 * 4, stream);
    k_bnstats<<<112, 256, 0, stream>>>(x0, stats);
    k_bnfinal<<<1, 128, 0, stream>>>(stats, bn0_g, bn0_b, scsh);
    k_apply_cat<<<cdiv(NPX * CM, 256), 256, 0, stream>>>(x0, scsh, nullptr, vinr);
    k_coords_r<<<cdiv(NPX, 256), 256, 0, stream>>>(vinr);

    // resblock 1
    k_gemm_nt<64, 64, 4, 4><<<dim3(392, 2), 256, 0, stream>>>(
        vinr, CR, r1c1_w, CR, nullptr, r1c1_b, v1, CM, NPX, CM, CR, 1);
    k_conv_pm<<<dim3(98, 8), 256, 0, stream>>>(v1, wpk1, r1c2_b, v2pre);
    hipMemsetAsync(stats, 0, 256 * 4, stream);
    k_bnstats<<<112, 256, 0, stream>>>(v2pre, stats);
    k_bnfinal<<<1, 128, 0, stream>>>(stats, r1bn_g, r1bn_b, scsh);
    k_apply_cat<<<cdiv(NPX * CM, 256), 256, 0, stream>>>(v2pre, scsh, v1, vinr);

    // resblock 2
    k_gemm_nt<64, 64, 4, 4><<<dim3(392, 2), 256, 0, stream>>>(
        vinr, CR, r2c1_w, CR, nullptr, r2c1_b, v1, CM, NPX, CM, CR, 1);
    k_conv_pm<<<dim3(98, 8), 256, 0, stream>>>(v1, wpk2, r2c2_b, v2pre);
    hipMemsetAsync(stats, 0, 256 * 4, stream);
    k_bnstats<<<112, 256, 0, stream>>>(v2pre, stats);
    k_bnfinal<<<1, 128, 0, stream>>>(stats, r2bn_g, r2bn_b, scsh);
    k_final<<<cdiv(NPX * CM, 256), 256, 0, stream>>>(v2pre, scsh, v1, out + (size_t)BB * 2048);
}